// Round 2
// baseline (99.310 us; speedup 1.0000x reference)
//
#include <hip/hip_runtime.h>
#include <hip/hip_bf16.h>

// ARAP local step: per (b,i) accumulate S = sum_j w * d1 d2^T over neighbors,
// then R = argmax_{R in SO(3)} trace(R*S) via Horn's quaternion method.
// Top eigenvector of the symmetric 4x4 N is found by repeated squaring of the
// shifted PD matrix M = N + s*I (s = 2*||S||_F > max|eig|): after 16
// squarings M^(2^16) ~= c*v*v^T, so the column with the largest diagonal
// entry IS the eigenvector. Handles arbitrarily small eigen-gaps (the
// failure mode of round-1's 40-step power iteration: ratio^40 left ~2e-2
// residual on the worst vertex).

__global__ __launch_bounds__(256)
void arap_rot_kernel(const float* __restrict__ xyz1,
                     const float* __restrict__ xyz2,
                     const int*   __restrict__ nbr,
                     const int*   __restrict__ num,
                     const int*   __restrict__ acc,
                     const float* __restrict__ wgt,
                     float*       __restrict__ out,
                     int B, int N)
{
    int t = blockIdx.x * blockDim.x + threadIdx.x;
    int total = B * N;
    if (t >= total) return;
    int b = t / N;
    int i = t - b * N;

    const float* x1 = xyz1 + (size_t)b * N * 3;
    const float* x2 = xyz2 + (size_t)b * N * 3;

    float p1x = x1[i * 3 + 0], p1y = x1[i * 3 + 1], p1z = x1[i * 3 + 2];
    float p2x = x2[i * 3 + 0], p2y = x2[i * 3 + 1], p2z = x2[i * 3 + 2];

    float Sxx = 0.f, Sxy = 0.f, Sxz = 0.f;
    float Syx = 0.f, Syy = 0.f, Syz = 0.f;
    float Szx = 0.f, Szy = 0.f, Szz = 0.f;

    int a0  = acc[i];
    int cnt = num[i];
#pragma unroll 4
    for (int k = 0; k < cnt; ++k) {
        int   e  = a0 + k;
        int   j  = nbr[e];
        float we = wgt[e];
        float d1x = p1x - x1[j * 3 + 0];
        float d1y = p1y - x1[j * 3 + 1];
        float d1z = p1z - x1[j * 3 + 2];
        float d2x = p2x - x2[j * 3 + 0];
        float d2y = p2y - x2[j * 3 + 1];
        float d2z = p2z - x2[j * 3 + 2];
        Sxx += we * d1x * d2x;  Sxy += we * d1x * d2y;  Sxz += we * d1x * d2z;
        Syx += we * d1y * d2x;  Syy += we * d1y * d2y;  Syz += we * d1y * d2z;
        Szx += we * d1z * d2x;  Szy += we * d1z * d2y;  Szz += we * d1z * d2z;
    }

    // Horn's 4x4 symmetric matrix (q = [w,x,y,z] basis); maps d1 -> d2.
    float n00 =  Sxx + Syy + Szz;
    float n01 =  Syz - Szy;
    float n02 =  Szx - Sxz;
    float n03 =  Sxy - Syx;
    float n11 =  Sxx - Syy - Szz;
    float n12 =  Sxy + Syx;
    float n13 =  Szx + Sxz;
    float n22 = -Sxx + Syy - Szz;
    float n23 =  Syz + Szy;
    float n33 = -Sxx - Syy + Szz;

    // Shift: all |eig(N)| <= sigma1+sigma2+sigma3 <= sqrt(3)*||S||_F < 2*||S||_F
    // => M = N + s*I is positive definite with top eigvec == Horn's quaternion.
    float fro2 = Sxx*Sxx + Sxy*Sxy + Sxz*Sxz
               + Syx*Syx + Syy*Syy + Syz*Syz
               + Szx*Szx + Szy*Szy + Szz*Szz;
    float s = 2.0f * sqrtf(fro2) + 1e-30f;

    float m00 = n00 + s, m01 = n01, m02 = n02, m03 = n03;
    float m11 = n11 + s, m12 = n12, m13 = n13;
    float m22 = n22 + s, m23 = n23;
    float m33 = n33 + s;

    // Normalize once by trace (positive), then 16 symmetric squarings with
    // trace renormalization: entries stay in [~0.06, 4], M stays PD.
    {
        float inv = 1.0f / (m00 + m11 + m22 + m33);
        m00 *= inv; m01 *= inv; m02 *= inv; m03 *= inv;
        m11 *= inv; m12 *= inv; m13 *= inv;
        m22 *= inv; m23 *= inv; m33 *= inv;
    }

#pragma unroll
    for (int it = 0; it < 16; ++it) {
        float p00 = m00*m00 + m01*m01 + m02*m02 + m03*m03;
        float p01 = m00*m01 + m01*m11 + m02*m12 + m03*m13;
        float p02 = m00*m02 + m01*m12 + m02*m22 + m03*m23;
        float p03 = m00*m03 + m01*m13 + m02*m23 + m03*m33;
        float p11 = m01*m01 + m11*m11 + m12*m12 + m13*m13;
        float p12 = m01*m02 + m11*m12 + m12*m22 + m13*m23;
        float p13 = m01*m03 + m11*m13 + m12*m23 + m13*m33;
        float p22 = m02*m02 + m12*m12 + m22*m22 + m23*m23;
        float p23 = m02*m03 + m12*m13 + m22*m23 + m23*m33;
        float p33 = m03*m03 + m13*m13 + m23*m23 + m33*m33;
        float inv = 1.0f / (p00 + p11 + p22 + p33);
        m00 = p00 * inv; m01 = p01 * inv; m02 = p02 * inv; m03 = p03 * inv;
        m11 = p11 * inv; m12 = p12 * inv; m13 = p13 * inv;
        m22 = p22 * inv; m23 = p23 * inv;
        m33 = p33 * inv;
    }

    // M ~= c * v v^T, c>0: diagonal entry k is c*v_k^2. Take the column with
    // the largest diagonal (branchless cndmask chain).
    float qw = m00, qx = m01, qy = m02, qz = m03, best = m00;
    {
        bool g = m11 > best;
        qw = g ? m01 : qw; qx = g ? m11 : qx; qy = g ? m12 : qy; qz = g ? m13 : qz;
        best = g ? m11 : best;
        g = m22 > best;
        qw = g ? m02 : qw; qx = g ? m12 : qx; qy = g ? m22 : qy; qz = g ? m23 : qz;
        best = g ? m22 : best;
        g = m33 > best;
        qw = g ? m03 : qw; qx = g ? m13 : qx; qy = g ? m23 : qy; qz = g ? m33 : qz;
    }
    {
        float inv = rsqrtf(qw*qw + qx*qx + qy*qy + qz*qz);
        qw *= inv; qx *= inv; qy *= inv; qz *= inv;
    }

    // Quaternion -> rotation matrix (R d1 ~= d2), row-major 3x3
    float xx = qx*qx, yy = qy*qy, zz = qz*qz;
    float xy = qx*qy, xz = qx*qz, yz = qy*qz;
    float wx = qw*qx, wy = qw*qy, wz = qw*qz;

    float* o = out + (size_t)t * 9;
    o[0] = 1.f - 2.f*(yy + zz);
    o[1] = 2.f*(xy - wz);
    o[2] = 2.f*(xz + wy);
    o[3] = 2.f*(xy + wz);
    o[4] = 1.f - 2.f*(xx + zz);
    o[5] = 2.f*(yz - wx);
    o[6] = 2.f*(xz - wy);
    o[7] = 2.f*(yz + wx);
    o[8] = 1.f - 2.f*(xx + yy);
}

extern "C" void kernel_launch(void* const* d_in, const int* in_sizes, int n_in,
                              void* d_out, int out_size, void* d_ws, size_t ws_size,
                              hipStream_t stream) {
    const float* xyz1 = (const float*)d_in[0];
    const float* xyz2 = (const float*)d_in[1];
    const int*   nbr  = (const int*)  d_in[2];
    const int*   num  = (const int*)  d_in[3];
    const int*   acc  = (const int*)  d_in[4];
    const float* wgt  = (const float*)d_in[5];
    // d_in[6] (rotations initial guess) and d_in[7] (arapWeight) do not affect
    // the fitted rotations in the reference math.
    float* out = (float*)d_out;

    int N = in_sizes[3];               // numNeighbors has N entries
    int B = in_sizes[0] / (N * 3);     // xyz1 is [B,N,3]
    int total = B * N;
    int block = 256;
    int grid = (total + block - 1) / block;
    arap_rot_kernel<<<grid, block, 0, stream>>>(xyz1, xyz2, nbr, num, acc, wgt,
                                                out, B, N);
}

// Round 3
// 94.007 us; speedup vs baseline: 1.0564x; 1.0564x over previous
//
#include <hip/hip_runtime.h>
#include <hip/hip_bf16.h>

// ARAP local step, round 3.
// Round-2 analysis: 96 address-divergent scalar dword gathers/thread dominate
// (TA processes ~64 unique cache lines per divergent VMEM instr). Fix: prepack
// xyz1/xyz2 into one 32B-per-vertex record so each neighbor gather is
// 2x global_load_dwordx4 hitting the SAME 64B line -> 32 gather instrs, 3x
// fewer address-divergent VMEM ops, plus int4/float4 coalesced idx/weight
// loads and full unroll for MLP.
// Eigensolve: Horn quaternion via 16 symmetric squarings of the shifted PD
// 4x4 (handles tiny eigen-gaps; verified round 2, absmax 3.9e-3).

__global__ __launch_bounds__(256)
void prepack_kernel(const float* __restrict__ xyz1,
                    const float* __restrict__ xyz2,
                    float4* __restrict__ pk,   // [B*N][2] float4
                    int total)
{
    int t = blockIdx.x * blockDim.x + threadIdx.x;
    if (t >= total) return;
    float4 a, c;
    a.x = xyz1[t * 3 + 0]; a.y = xyz1[t * 3 + 1]; a.z = xyz1[t * 3 + 2]; a.w = 0.f;
    c.x = xyz2[t * 3 + 0]; c.y = xyz2[t * 3 + 1]; c.z = xyz2[t * 3 + 2]; c.w = 0.f;
    pk[2 * (size_t)t + 0] = a;
    pk[2 * (size_t)t + 1] = c;
}

__global__ __launch_bounds__(256)
void arap_rot_kernel(const float4* __restrict__ pk,
                     const int*   __restrict__ nbr,
                     const int*   __restrict__ num,
                     const int*   __restrict__ acc,
                     const float* __restrict__ wgt,
                     float*       __restrict__ out,
                     int B, int N)
{
    int t = blockIdx.x * blockDim.x + threadIdx.x;
    int total = B * N;
    if (t >= total) return;
    int b = t / N;
    int i = t - b * N;

    const float4* base = pk + 2 * (size_t)b * N;

    float4 P1 = base[2 * i + 0];
    float4 P2 = base[2 * i + 1];
    float p1x = P1.x, p1y = P1.y, p1z = P1.z;
    float p2x = P2.x, p2y = P2.y, p2z = P2.z;

    float Sxx = 0.f, Sxy = 0.f, Sxz = 0.f;
    float Syx = 0.f, Syy = 0.f, Syz = 0.f;
    float Szx = 0.f, Szy = 0.f, Szz = 0.f;

    int a0  = acc[i];
    int cnt = num[i];

    if (cnt == 16 && (a0 & 3) == 0) {
        // Fast path: 4 int4 index loads, 4 float4 weight loads, 32 dwordx4
        // gathers (pairs share a 64B line). Fully unrolled for MLP.
        const int4*   nb4 = (const int4*)(nbr + a0);
        const float4* w4  = (const float4*)(wgt + a0);
#pragma unroll
        for (int c = 0; c < 4; ++c) {
            int4   jj = nb4[c];
            float4 ww = w4[c];
            int js[4] = {jj.x, jj.y, jj.z, jj.w};
            float ws[4] = {ww.x, ww.y, ww.z, ww.w};
#pragma unroll
            for (int u = 0; u < 4; ++u) {
                int j = js[u];
                float4 A = base[2 * j + 0];
                float4 C = base[2 * j + 1];
                float we = ws[u];
                float d1x = p1x - A.x, d1y = p1y - A.y, d1z = p1z - A.z;
                float d2x = p2x - C.x, d2y = p2y - C.y, d2z = p2z - C.z;
                float w1x = we * d1x, w1y = we * d1y, w1z = we * d1z;
                Sxx += w1x * d2x;  Sxy += w1x * d2y;  Sxz += w1x * d2z;
                Syx += w1y * d2x;  Syy += w1y * d2y;  Syz += w1y * d2z;
                Szx += w1z * d2x;  Szy += w1z * d2y;  Szz += w1z * d2z;
            }
        }
    } else {
        for (int k = 0; k < cnt; ++k) {
            int   e  = a0 + k;
            int   j  = nbr[e];
            float we = wgt[e];
            float4 A = base[2 * j + 0];
            float4 C = base[2 * j + 1];
            float d1x = p1x - A.x, d1y = p1y - A.y, d1z = p1z - A.z;
            float d2x = p2x - C.x, d2y = p2y - C.y, d2z = p2z - C.z;
            float w1x = we * d1x, w1y = we * d1y, w1z = we * d1z;
            Sxx += w1x * d2x;  Sxy += w1x * d2y;  Sxz += w1x * d2z;
            Syx += w1y * d2x;  Syy += w1y * d2y;  Syz += w1y * d2z;
            Szx += w1z * d2x;  Szy += w1z * d2y;  Szz += w1z * d2z;
        }
    }

    // Horn's 4x4 symmetric matrix (q = [w,x,y,z] basis); maps d1 -> d2.
    float n00 =  Sxx + Syy + Szz;
    float n01 =  Syz - Szy;
    float n02 =  Szx - Sxz;
    float n03 =  Sxy - Syx;
    float n11 =  Sxx - Syy - Szz;
    float n12 =  Sxy + Syx;
    float n13 =  Szx + Sxz;
    float n22 = -Sxx + Syy - Szz;
    float n23 =  Syz + Szy;
    float n33 = -Sxx - Syy + Szz;

    // Shift: all |eig(N)| <= sqrt(3)*||S||_F < 2*||S||_F  => M = N+sI is PD,
    // top eigvec of M == Horn's quaternion.
    float fro2 = Sxx*Sxx + Sxy*Sxy + Sxz*Sxz
               + Syx*Syx + Syy*Syy + Syz*Syz
               + Szx*Szx + Szy*Szy + Szz*Szz;
    float s = 2.0f * sqrtf(fro2) + 1e-30f;

    float m00 = n00 + s, m01 = n01, m02 = n02, m03 = n03;
    float m11 = n11 + s, m12 = n12, m13 = n13;
    float m22 = n22 + s, m23 = n23;
    float m33 = n33 + s;

    {
        float inv = 1.0f / (m00 + m11 + m22 + m33);
        m00 *= inv; m01 *= inv; m02 *= inv; m03 *= inv;
        m11 *= inv; m12 *= inv; m13 *= inv;
        m22 *= inv; m23 *= inv; m33 *= inv;
    }

    // 16 symmetric squarings with trace renormalization: M^(2^16) -> c*v*v^T.
#pragma unroll
    for (int it = 0; it < 16; ++it) {
        float p00 = m00*m00 + m01*m01 + m02*m02 + m03*m03;
        float p01 = m00*m01 + m01*m11 + m02*m12 + m03*m13;
        float p02 = m00*m02 + m01*m12 + m02*m22 + m03*m23;
        float p03 = m00*m03 + m01*m13 + m02*m23 + m03*m33;
        float p11 = m01*m01 + m11*m11 + m12*m12 + m13*m13;
        float p12 = m01*m02 + m11*m12 + m12*m22 + m13*m23;
        float p13 = m01*m03 + m11*m13 + m12*m23 + m13*m33;
        float p22 = m02*m02 + m12*m12 + m22*m22 + m23*m23;
        float p23 = m02*m03 + m12*m13 + m22*m23 + m23*m33;
        float p33 = m03*m03 + m13*m13 + m23*m23 + m33*m33;
        float inv = 1.0f / (p00 + p11 + p22 + p33);
        m00 = p00 * inv; m01 = p01 * inv; m02 = p02 * inv; m03 = p03 * inv;
        m11 = p11 * inv; m12 = p12 * inv; m13 = p13 * inv;
        m22 = p22 * inv; m23 = p23 * inv;
        m33 = p33 * inv;
    }

    // Column with the largest diagonal entry == top eigenvector.
    float qw = m00, qx = m01, qy = m02, qz = m03, best = m00;
    {
        bool g = m11 > best;
        qw = g ? m01 : qw; qx = g ? m11 : qx; qy = g ? m12 : qy; qz = g ? m13 : qz;
        best = g ? m11 : best;
        g = m22 > best;
        qw = g ? m02 : qw; qx = g ? m12 : qx; qy = g ? m22 : qy; qz = g ? m23 : qz;
        best = g ? m22 : best;
        g = m33 > best;
        qw = g ? m03 : qw; qx = g ? m13 : qx; qy = g ? m23 : qy; qz = g ? m33 : qz;
    }
    {
        float inv = rsqrtf(qw*qw + qx*qx + qy*qy + qz*qz);
        qw *= inv; qx *= inv; qy *= inv; qz *= inv;
    }

    // Quaternion -> rotation matrix (R d1 ~= d2), row-major 3x3
    float xx = qx*qx, yy = qy*qy, zz = qz*qz;
    float xy = qx*qy, xz = qx*qz, yz = qy*qz;
    float wx = qw*qx, wy = qw*qy, wz = qw*qz;

    float* o = out + (size_t)t * 9;
    o[0] = 1.f - 2.f*(yy + zz);
    o[1] = 2.f*(xy - wz);
    o[2] = 2.f*(xz + wy);
    o[3] = 2.f*(xy + wz);
    o[4] = 1.f - 2.f*(xx + zz);
    o[5] = 2.f*(yz - wx);
    o[6] = 2.f*(xz - wy);
    o[7] = 2.f*(yz + wx);
    o[8] = 1.f - 2.f*(xx + yy);
}

extern "C" void kernel_launch(void* const* d_in, const int* in_sizes, int n_in,
                              void* d_out, int out_size, void* d_ws, size_t ws_size,
                              hipStream_t stream) {
    const float* xyz1 = (const float*)d_in[0];
    const float* xyz2 = (const float*)d_in[1];
    const int*   nbr  = (const int*)  d_in[2];
    const int*   num  = (const int*)  d_in[3];
    const int*   acc  = (const int*)  d_in[4];
    const float* wgt  = (const float*)d_in[5];
    float* out = (float*)d_out;

    int N = in_sizes[3];               // numNeighbors has N entries
    int B = in_sizes[0] / (N * 3);     // xyz1 is [B,N,3]
    int total = B * N;

    float4* pk = (float4*)d_ws;        // [total][2] float4 = 32B/vertex

    int block = 256;
    int grid = (total + block - 1) / block;
    prepack_kernel<<<grid, block, 0, stream>>>(xyz1, xyz2, pk, total);
    arap_rot_kernel<<<grid, block, 0, stream>>>(pk, nbr, num, acc, wgt,
                                                out, B, N);
}